// Round 8
// baseline (175.425 us; speedup 1.0000x reference)
//
#include <hip/hip_runtime.h>
#include <hip/hip_cooperative_groups.h>

namespace cg = cooperative_groups;

#define NUM_LABELS 20
#define N_PIX 4096
#define C_DIM 16
#define BATCH 4

#define PTILE 128
#define PNT (N_PIX / PTILE)               // 32
#define PTPAIRS (PNT * (PNT + 1) / 2)     // 528
#define NPAIRS (BATCH * PTPAIRS)          // 2112
#define NBLK 704                          // 704 * 3 = 2112
#define PAIRS_PER_BLK 3
#define KPAD 24                           // LDS row stride in shorts (48 B)

#define HIST_BLKS 64                      // 16 slices per batch
#define SLICES_PB 16

typedef __attribute__((ext_vector_type(8))) short bf16x8;
typedef __attribute__((ext_vector_type(4))) float f32x4;

__device__ __forceinline__ unsigned int bf16rne(float f) {
    unsigned int x = __float_as_uint(f);
    return (x + 0x7fffu + ((x >> 16) & 1u)) >> 16;
}

// Single cooperative kernel:
//   out = [ 0.5*sum_b P_b - 0.5*sum_i |g_i|^2 + sum_b sum_{i<j} (eq ? -s : max(s,0)) ] / N
// g = (1/cnt[y]) * normalize(center(x)), s = bf16(g_i).bf16(g_j) via MFMA.
__global__ __launch_bounds__(256, 3) void fused_kernel(
    const float* __restrict__ emb,        // [B][C][N]
    const int*   __restrict__ lab,        // [B][N]
    int*   __restrict__ hist_sl,          // [HIST_BLKS][NUM_LABELS]
    float* __restrict__ partials,         // [NBLK]
    float* __restrict__ out)              // [1]
{
    const int bk   = blockIdx.x;
    const int t    = threadIdx.x;
    const int lane = t & 63;
    const int wv   = t >> 6;

    __shared__ float rinv[BATCH][NUM_LABELS];
    __shared__ unsigned short sI[PTILE * KPAD];
    __shared__ unsigned short sJ[PTILE * KPAD];
    __shared__ int   syI[PTILE], syJ[PTILE];
    __shared__ float wred[4];
    __shared__ double sd[256];

    // ---- Phase A: distributed histogram (64 blocks, 256 pixels each) -------
    if (bk < HIST_BLKS) {
        __shared__ int h[4][NUM_LABELS];
        for (int i = t; i < 4 * NUM_LABELS; i += 256) (&h[0][0])[i] = 0;
        __syncthreads();
        const int b  = bk / SLICES_PB;
        const int sl = bk % SLICES_PB;
        const int y  = lab[b * N_PIX + sl * 256 + t];
        atomicAdd(&h[wv][y], 1);
        __syncthreads();
        if (t < NUM_LABELS)
            hist_sl[bk * NUM_LABELS + t] = h[0][t] + h[1][t] + h[2][t] + h[3][t];
    }

    cg::this_grid().sync();

    // ---- every block: build rinv[4][20] from the 64 slices ------------------
    if (t < BATCH * NUM_LABELS) {
        const int b = t / NUM_LABELS, l = t % NUM_LABELS;
        int c = 0;
#pragma unroll
        for (int s = 0; s < SLICES_PB; ++s)
            c += hist_sl[(b * SLICES_PB + s) * NUM_LABELS + l];
        rinv[b][l] = (c > 0) ? 1.0f / (float)c : 0.0f;
    }
    __syncthreads();

    float sum = 0.f;
    if (bk == 0 && t == 0) {             // + 0.5 * sum_b (#present labels)
        int p = 0;
#pragma unroll
        for (int b = 0; b < BATCH; ++b)
#pragma unroll
            for (int l = 0; l < NUM_LABELS; ++l)
                p += (rinv[b][l] > 0.f) ? 1 : 0;
        sum += 0.5f * (float)p;
    }

    // ---- Phase B: 3 tile-pairs per block ------------------------------------
    for (int pi = 0; pi < PAIRS_PER_BLK; ++pi) {
        const int p  = bk + pi * NBLK;
        const int b  = p / PTPAIRS;
        int k0 = p % PTPAIRS;

        // decode upper-triangle tile pair (ti <= tj)
        const float nn = (float)PNT;
        int ti = (int)(((2.f * nn + 1.f) -
                        sqrtf((2.f * nn + 1.f) * (2.f * nn + 1.f) - 8.f * (float)k0)) * 0.5f);
        if (ti < 0) ti = 0;
        if (ti > PNT - 1) ti = PNT - 1;
        auto rowoff = [](int r) { return r * PNT - (r * (r - 1)) / 2; };
        while (ti > 0 && k0 < rowoff(ti)) --ti;
        while (ti < PNT - 1 && k0 >= rowoff(ti + 1)) ++ti;
        const int tj = ti + (k0 - rowoff(ti));
        const bool diag = (ti == tj);

        __syncthreads();   // previous iteration's LDS reads done

        // ---- normalize own tiles straight from emb into LDS bf16 ----------
        {
            const int side = t >> 7;          // 0 -> tile I, 1 -> tile J
            const int row  = t & 127;
            const int tile = side ? tj : ti;
            const int gidx = b * N_PIX + tile * PTILE + row;
            const float* xb = emb + (size_t)b * C_DIM * N_PIX + tile * PTILE + row;

            float v[C_DIM];
            float s = 0.f;
#pragma unroll
            for (int c = 0; c < C_DIM; ++c) { v[c] = xb[(size_t)c * N_PIX]; s += v[c]; }
            const float mean = s * (1.0f / C_DIM);
            float ss = 0.f;
#pragma unroll
            for (int c = 0; c < C_DIM; ++c) { v[c] -= mean; ss += v[c] * v[c]; }
            const float nrm = sqrtf(ss);
            const int   y   = lab[gidx];
            const float w   = rinv[b][y];
            const float inv = (nrm > 0.f) ? (w / nrm) : 0.f;

            unsigned int u[8];
#pragma unroll
            for (int k = 0; k < 8; ++k) {
                const unsigned int lo = bf16rne(v[2 * k] * inv);
                const unsigned int hi = bf16rne(v[2 * k + 1] * inv);
                u[k] = lo | (hi << 16);
            }
            unsigned short* dst = side ? sJ : sI;
            *reinterpret_cast<uint4*>(&dst[row * KPAD])     = make_uint4(u[0], u[1], u[2], u[3]);
            *reinterpret_cast<uint4*>(&dst[row * KPAD + 8]) = make_uint4(u[4], u[5], u[6], u[7]);
            (side ? syJ : syI)[row] = y;

            // diagonal blocks own the -0.5*|g_f32|^2 term for their tile
            if (diag && side == 0) sum -= 0.5f * (inv * inv * ss);
        }
        __syncthreads();

        // ---- MFMA + epilogue ----------------------------------------------
        const int lo16 = lane & 15;
        const int hi   = lane >> 4;            // 0..3
        const bool doread = (hi < 2);          // K=16 real; hi>=2 lanes zero

        bf16x8 afrag[2] = {bf16x8{}, bf16x8{}};
        int    yIr[2][4];
#pragma unroll
        for (int rt = 0; rt < 2; ++rt) {
            const int rtile = wv * 2 + rt;
            if (doread)
                afrag[rt] = *reinterpret_cast<const bf16x8*>(&sI[(rtile * 16 + lo16) * KPAD + hi * 8]);
            const int4 yv = *reinterpret_cast<const int4*>(&syI[rtile * 16 + hi * 4]);
            yIr[rt][0] = yv.x; yIr[rt][1] = yv.y; yIr[rt][2] = yv.z; yIr[rt][3] = yv.w;
        }

#pragma unroll
        for (int ct = 0; ct < 8; ++ct) {
            bf16x8 bfrag = bf16x8{};
            if (doread)
                bfrag = *reinterpret_cast<const bf16x8*>(&sJ[(ct * 16 + lo16) * KPAD + hi * 8]);
            const int yq = syJ[ct * 16 + lo16];
#pragma unroll
            for (int rt = 0; rt < 2; ++rt) {
                const int rtile = wv * 2 + rt;
                if (diag && rtile > ct) continue;      // below diagonal: skip
                f32x4 acc = {0.f, 0.f, 0.f, 0.f};
                acc = __builtin_amdgcn_mfma_f32_16x16x32_bf16(afrag[rt], bfrag, acc, 0, 0, 0);
                if (diag && rtile == ct) {
#pragma unroll
                    for (int j = 0; j < 4; ++j) {
                        const float s = acc[j];
                        const float v = (yIr[rt][j] == yq) ? -s : fmaxf(s, 0.f);
                        const int iloc = hi * 4 + j;
                        sum += (iloc < lo16) ? v : 0.f;   // strict i<j
                    }
                } else {
#pragma unroll
                    for (int j = 0; j < 4; ++j) {
                        const float s = acc[j];
                        sum += (yIr[rt][j] == yq) ? -s : fmaxf(s, 0.f);
                    }
                }
            }
        }
    }

    // ---- block reduction ---------------------------------------------------
#pragma unroll
    for (int off = 32; off > 0; off >>= 1) sum += __shfl_down(sum, off);
    if (lane == 0) wred[wv] = sum;
    __syncthreads();
    if (t == 0) partials[bk] = wred[0] + wred[1] + wred[2] + wred[3];

    // ---- grid-wide barrier, block 0 reduces deterministically --------------
    cg::this_grid().sync();

    if (bk == 0) {
        double s = 0.0;
        for (int i = t; i < NBLK; i += 256) s += (double)partials[i];
        sd[t] = s;
        __syncthreads();
#pragma unroll
        for (int k = 128; k > 0; k >>= 1) {
            if (t < k) sd[t] += sd[t + k];
            __syncthreads();
        }
        if (t == 0) out[0] = (float)(sd[0] * (1.0 / (double)N_PIX));
    }
}

extern "C" void kernel_launch(void* const* d_in, const int* in_sizes, int n_in,
                              void* d_out, int out_size, void* d_ws, size_t ws_size,
                              hipStream_t stream) {
    const float* emb = (const float*)d_in[0];
    const int*   lab = (const int*)d_in[1];
    float* out = (float*)d_out;

    int*   hist_sl  = (int*)d_ws;                        // 64*20 ints
    float* partials = (float*)(hist_sl + HIST_BLKS * NUM_LABELS);   // NBLK floats

    void* args[] = {(void*)&emb, (void*)&lab, (void*)&hist_sl, (void*)&partials, (void*)&out};
    hipLaunchCooperativeKernel((const void*)fused_kernel,
                               dim3(NBLK), dim3(256), args, 0, stream);
}

// Round 9
// 45.293 us; speedup vs baseline: 3.8731x; 3.8731x over previous
//
#include <hip/hip_runtime.h>

#define NUM_LABELS 20
#define N_PIX 4096
#define C_DIM 16
#define BATCH 4

#define PTILE 128
#define PNT (N_PIX / PTILE)               // 32
#define PTPAIRS (PNT * (PNT + 1) / 2)     // 528
#define NPAIRS (BATCH * PTPAIRS)          // 2112
#define KPAD 24                           // LDS row stride in shorts (48 B)

typedef __attribute__((ext_vector_type(8))) short bf16x8;
typedef __attribute__((ext_vector_type(4))) float f32x4;

__device__ __forceinline__ unsigned int bf16rne(float f) {
    unsigned int x = __float_as_uint(f);
    return (x + 0x7fffu + ((x >> 16) & 1u)) >> 16;
}

// ---------------- Kernel 1: per-batch histogram -> rinv; + present-label term
__global__ __launch_bounds__(1024) void hist_kernel(
    const int* __restrict__ lab,          // [B][N]
    float* __restrict__ rinv_g,           // [BATCH][NUM_LABELS]
    float* __restrict__ out)              // [1] (pre-zeroed via memset node)
{
    const int b = blockIdx.x;
    const int t = threadIdx.x;
    const int wv = t >> 6;                // 0..15

    __shared__ int h[16][NUM_LABELS];
    for (int i = t; i < 16 * NUM_LABELS; i += 1024) (&h[0][0])[i] = 0;
    __syncthreads();

    const int* yb = lab + (size_t)b * N_PIX;
    for (int n = t; n < N_PIX; n += 1024) atomicAdd(&h[wv][yb[n]], 1);
    __syncthreads();

    if (t < NUM_LABELS) {
        int c = 0;
#pragma unroll
        for (int s = 0; s < 16; ++s) c += h[s][t];
        rinv_g[b * NUM_LABELS + t] = (c > 0) ? 1.0f / (float)c : 0.0f;
        h[0][t] = (c > 0) ? 1 : 0;        // reuse slab for present flags
    }
    __syncthreads();
    if (t == 0) {
        int p = 0;
#pragma unroll
        for (int l = 0; l < NUM_LABELS; ++l) p += h[0][l];
        atomicAdd(out, 0.5f * (float)p * (1.0f / (float)N_PIX));
    }
}

// ---------------- Kernel 2: normalize own tiles + MFMA + epilogue + atomic --
// block partial = sum_{i<j in tile-pair} (eq ? -s : max(s,0))
//                 [diag blocks also own -0.5*|g_f32|^2 for their tile]
// out += partial / N
__global__ __launch_bounds__(256) void pair_kernel(
    const float* __restrict__ emb,        // [B][C][N]
    const int*   __restrict__ lab,        // [B][N]
    const float* __restrict__ rinv_g,     // [BATCH][NUM_LABELS]
    float* __restrict__ out)              // [1]
{
    const int p  = blockIdx.x;
    const int b  = p / PTPAIRS;
    const int k0 = p % PTPAIRS;

    // decode upper-triangle tile pair (ti <= tj)
    const float nn = (float)PNT;
    int ti = (int)(((2.f * nn + 1.f) -
                    sqrtf((2.f * nn + 1.f) * (2.f * nn + 1.f) - 8.f * (float)k0)) * 0.5f);
    if (ti < 0) ti = 0;
    if (ti > PNT - 1) ti = PNT - 1;
    auto rowoff = [](int r) { return r * PNT - (r * (r - 1)) / 2; };
    while (ti > 0 && k0 < rowoff(ti)) --ti;
    while (ti < PNT - 1 && k0 >= rowoff(ti + 1)) ++ti;
    const int tj = ti + (k0 - rowoff(ti));
    const bool diag = (ti == tj);

    const int t    = threadIdx.x;
    const int lane = t & 63;
    const int wv   = t >> 6;

    __shared__ float rl[NUM_LABELS];
    __shared__ unsigned short sI[PTILE * KPAD];
    __shared__ unsigned short sJ[PTILE * KPAD];
    __shared__ int   syI[PTILE], syJ[PTILE];
    __shared__ float wred[4];

    if (t < NUM_LABELS) rl[t] = rinv_g[b * NUM_LABELS + t];
    __syncthreads();

    float sum = 0.f;

    // ---- normalize own tiles straight from emb into LDS bf16 ---------------
    {
        const int side = t >> 7;          // 0 -> tile I, 1 -> tile J
        const int row  = t & 127;
        const int tile = side ? tj : ti;
        const float* xb = emb + (size_t)b * C_DIM * N_PIX + tile * PTILE + row;

        float v[C_DIM];
        float s = 0.f;
#pragma unroll
        for (int c = 0; c < C_DIM; ++c) { v[c] = xb[(size_t)c * N_PIX]; s += v[c]; }
        const float mean = s * (1.0f / C_DIM);
        float ss = 0.f;
#pragma unroll
        for (int c = 0; c < C_DIM; ++c) { v[c] -= mean; ss += v[c] * v[c]; }
        const float nrm = sqrtf(ss);
        const int   y   = lab[b * N_PIX + tile * PTILE + row];
        const float w   = rl[y];
        const float inv = (nrm > 0.f) ? (w / nrm) : 0.f;

        unsigned int u[8];
#pragma unroll
        for (int k = 0; k < 8; ++k) {
            const unsigned int lo = bf16rne(v[2 * k] * inv);
            const unsigned int hi = bf16rne(v[2 * k + 1] * inv);
            u[k] = lo | (hi << 16);
        }
        unsigned short* dst = side ? sJ : sI;
        *reinterpret_cast<uint4*>(&dst[row * KPAD])     = make_uint4(u[0], u[1], u[2], u[3]);
        *reinterpret_cast<uint4*>(&dst[row * KPAD + 8]) = make_uint4(u[4], u[5], u[6], u[7]);
        (side ? syJ : syI)[row] = y;

        if (diag && side == 0) sum -= 0.5f * (inv * inv * ss);
    }
    __syncthreads();

    // ---- MFMA + epilogue ----------------------------------------------------
    const int lo16 = lane & 15;
    const int hi   = lane >> 4;            // 0..3
    const bool doread = (hi < 2);          // K=16 real; hi>=2 lanes hold zeros

    bf16x8 afrag[2] = {bf16x8{}, bf16x8{}};
    int    yIr[2][4];
#pragma unroll
    for (int rt = 0; rt < 2; ++rt) {
        const int rtile = wv * 2 + rt;
        if (doread)
            afrag[rt] = *reinterpret_cast<const bf16x8*>(&sI[(rtile * 16 + lo16) * KPAD + hi * 8]);
        const int4 yv = *reinterpret_cast<const int4*>(&syI[rtile * 16 + hi * 4]);
        yIr[rt][0] = yv.x; yIr[rt][1] = yv.y; yIr[rt][2] = yv.z; yIr[rt][3] = yv.w;
    }

#pragma unroll
    for (int ct = 0; ct < 8; ++ct) {
        bf16x8 bfrag = bf16x8{};
        if (doread)
            bfrag = *reinterpret_cast<const bf16x8*>(&sJ[(ct * 16 + lo16) * KPAD + hi * 8]);
        const int yq = syJ[ct * 16 + lo16];
#pragma unroll
        for (int rt = 0; rt < 2; ++rt) {
            const int rtile = wv * 2 + rt;
            if (diag && rtile > ct) continue;      // below diagonal: skip
            f32x4 acc = {0.f, 0.f, 0.f, 0.f};
            acc = __builtin_amdgcn_mfma_f32_16x16x32_bf16(afrag[rt], bfrag, acc, 0, 0, 0);
            if (diag && rtile == ct) {
#pragma unroll
                for (int j = 0; j < 4; ++j) {
                    const float s = acc[j];
                    const float v = (yIr[rt][j] == yq) ? -s : fmaxf(s, 0.f);
                    const int iloc = hi * 4 + j;
                    sum += (iloc < lo16) ? v : 0.f;   // strict i<j
                }
            } else {
#pragma unroll
                for (int j = 0; j < 4; ++j) {
                    const float s = acc[j];
                    sum += (yIr[rt][j] == yq) ? -s : fmaxf(s, 0.f);
                }
            }
        }
    }

    // ---- block reduction + single atomic ------------------------------------
#pragma unroll
    for (int off = 32; off > 0; off >>= 1) sum += __shfl_down(sum, off);
    if (lane == 0) wred[wv] = sum;
    __syncthreads();
    if (t == 0) {
        const float total = wred[0] + wred[1] + wred[2] + wred[3];
        atomicAdd(out, total * (1.0f / (float)N_PIX));
    }
}

extern "C" void kernel_launch(void* const* d_in, const int* in_sizes, int n_in,
                              void* d_out, int out_size, void* d_ws, size_t ws_size,
                              hipStream_t stream) {
    const float* emb = (const float*)d_in[0];
    const int*   lab = (const int*)d_in[1];
    float* out = (float*)d_out;
    float* rinv_g = (float*)d_ws;          // BATCH*NUM_LABELS floats

    hipMemsetAsync(out, 0, sizeof(float), stream);
    hist_kernel<<<BATCH, 1024, 0, stream>>>(lab, rinv_g, out);
    pair_kernel<<<NPAIRS, 256, 0, stream>>>(emb, lab, rinv_g, out);
}

// Round 10
// 43.246 us; speedup vs baseline: 4.0565x; 1.0473x over previous
//
#include <hip/hip_runtime.h>

#define NUM_LABELS 20
#define N_PIX 4096
#define C_DIM 16
#define BATCH 4

#define PTILE 128
#define PNT (N_PIX / PTILE)               // 32
#define PTPAIRS (PNT * (PNT + 1) / 2)     // 528
#define NPAIRS (BATCH * PTPAIRS)          // 2112
#define KPAD 24                           // LDS row stride in shorts (48 B)

typedef __attribute__((ext_vector_type(8))) short bf16x8;
typedef __attribute__((ext_vector_type(4))) float f32x4;

__device__ __forceinline__ unsigned int bf16rne(float f) {
    unsigned int x = __float_as_uint(f);
    return (x + 0x7fffu + ((x >> 16) & 1u)) >> 16;
}

// ---------------- Kernel 1 (1 block): all-batch histogram -> rinv; init out -
// out[0] = 0.5 * sum_b (#present labels in batch b) / N    (plain store)
__global__ __launch_bounds__(1024) void hist_kernel(
    const int* __restrict__ lab,          // [B][N]
    float* __restrict__ rinv_g,           // [BATCH][NUM_LABELS]
    float* __restrict__ out)              // [1]
{
    const int t  = threadIdx.x;
    const int wv = t >> 6;                // 0..15

    __shared__ int h[16][BATCH * NUM_LABELS];
    __shared__ int pres[BATCH * NUM_LABELS];
    for (int i = t; i < 16 * BATCH * NUM_LABELS; i += 1024) (&h[0][0])[i] = 0;
    __syncthreads();

    for (int i = t; i < BATCH * N_PIX; i += 1024) {
        const int b = i >> 12;            // i / N_PIX
        const int y = lab[i];
        atomicAdd(&h[wv][b * NUM_LABELS + y], 1);
    }
    __syncthreads();

    if (t < BATCH * NUM_LABELS) {
        int c = 0;
#pragma unroll
        for (int s = 0; s < 16; ++s) c += h[s][t];
        rinv_g[t] = (c > 0) ? 1.0f / (float)c : 0.0f;
        pres[t]   = (c > 0) ? 1 : 0;
    }
    __syncthreads();
    if (t == 0) {
        int p = 0;
#pragma unroll
        for (int i = 0; i < BATCH * NUM_LABELS; ++i) p += pres[i];
        out[0] = 0.5f * (float)p * (1.0f / (float)N_PIX);   // fresh store every call
    }
}

// ---------------- Kernel 2: normalize own tiles + MFMA + epilogue + atomic --
// block partial = sum_{i<j in tile-pair} (eq ? -s : max(s,0))
//                 [diag blocks also own -0.5*|g_f32|^2 for their tile]
// out += partial / N
__global__ __launch_bounds__(256) void pair_kernel(
    const float* __restrict__ emb,        // [B][C][N]
    const int*   __restrict__ lab,        // [B][N]
    const float* __restrict__ rinv_g,     // [BATCH][NUM_LABELS]
    float* __restrict__ out)              // [1]
{
    const int p  = blockIdx.x;
    const int b  = p / PTPAIRS;
    const int k0 = p % PTPAIRS;

    // decode upper-triangle tile pair (ti <= tj)
    const float nn = (float)PNT;
    int ti = (int)(((2.f * nn + 1.f) -
                    sqrtf((2.f * nn + 1.f) * (2.f * nn + 1.f) - 8.f * (float)k0)) * 0.5f);
    if (ti < 0) ti = 0;
    if (ti > PNT - 1) ti = PNT - 1;
    auto rowoff = [](int r) { return r * PNT - (r * (r - 1)) / 2; };
    while (ti > 0 && k0 < rowoff(ti)) --ti;
    while (ti < PNT - 1 && k0 >= rowoff(ti + 1)) ++ti;
    const int tj = ti + (k0 - rowoff(ti));
    const bool diag = (ti == tj);

    const int t    = threadIdx.x;
    const int lane = t & 63;
    const int wv   = t >> 6;

    __shared__ float rl[NUM_LABELS];
    __shared__ unsigned short sI[PTILE * KPAD];
    __shared__ unsigned short sJ[PTILE * KPAD];
    __shared__ int   syI[PTILE], syJ[PTILE];
    __shared__ float wred[4];

    if (t < NUM_LABELS) rl[t] = rinv_g[b * NUM_LABELS + t];
    __syncthreads();

    float sum = 0.f;

    // ---- normalize own tiles straight from emb into LDS bf16 ---------------
    {
        const int side = t >> 7;          // 0 -> tile I, 1 -> tile J
        const int row  = t & 127;
        const int tile = side ? tj : ti;
        const float* xb = emb + (size_t)b * C_DIM * N_PIX + tile * PTILE + row;

        float v[C_DIM];
        float s = 0.f;
#pragma unroll
        for (int c = 0; c < C_DIM; ++c) { v[c] = xb[(size_t)c * N_PIX]; s += v[c]; }
        const float mean = s * (1.0f / C_DIM);
        float ss = 0.f;
#pragma unroll
        for (int c = 0; c < C_DIM; ++c) { v[c] -= mean; ss += v[c] * v[c]; }
        const float nrm = sqrtf(ss);
        const int   y   = lab[b * N_PIX + tile * PTILE + row];
        const float w   = rl[y];
        const float inv = (nrm > 0.f) ? (w / nrm) : 0.f;

        unsigned int u[8];
#pragma unroll
        for (int k = 0; k < 8; ++k) {
            const unsigned int lo = bf16rne(v[2 * k] * inv);
            const unsigned int hi = bf16rne(v[2 * k + 1] * inv);
            u[k] = lo | (hi << 16);
        }
        unsigned short* dst = side ? sJ : sI;
        *reinterpret_cast<uint4*>(&dst[row * KPAD])     = make_uint4(u[0], u[1], u[2], u[3]);
        *reinterpret_cast<uint4*>(&dst[row * KPAD + 8]) = make_uint4(u[4], u[5], u[6], u[7]);
        (side ? syJ : syI)[row] = y;

        if (diag && side == 0) sum -= 0.5f * (inv * inv * ss);
    }
    __syncthreads();

    // ---- MFMA + epilogue ----------------------------------------------------
    const int lo16 = lane & 15;
    const int hi   = lane >> 4;            // 0..3
    const bool doread = (hi < 2);          // K=16 real; hi>=2 lanes hold zeros

    bf16x8 afrag[2] = {bf16x8{}, bf16x8{}};
    int    yIr[2][4];
#pragma unroll
    for (int rt = 0; rt < 2; ++rt) {
        const int rtile = wv * 2 + rt;
        if (doread)
            afrag[rt] = *reinterpret_cast<const bf16x8*>(&sI[(rtile * 16 + lo16) * KPAD + hi * 8]);
        const int4 yv = *reinterpret_cast<const int4*>(&syI[rtile * 16 + hi * 4]);
        yIr[rt][0] = yv.x; yIr[rt][1] = yv.y; yIr[rt][2] = yv.z; yIr[rt][3] = yv.w;
    }

#pragma unroll
    for (int ct = 0; ct < 8; ++ct) {
        bf16x8 bfrag = bf16x8{};
        if (doread)
            bfrag = *reinterpret_cast<const bf16x8*>(&sJ[(ct * 16 + lo16) * KPAD + hi * 8]);
        const int yq = syJ[ct * 16 + lo16];
#pragma unroll
        for (int rt = 0; rt < 2; ++rt) {
            const int rtile = wv * 2 + rt;
            if (diag && rtile > ct) continue;      // below diagonal: skip
            f32x4 acc = {0.f, 0.f, 0.f, 0.f};
            acc = __builtin_amdgcn_mfma_f32_16x16x32_bf16(afrag[rt], bfrag, acc, 0, 0, 0);
            if (diag && rtile == ct) {
#pragma unroll
                for (int j = 0; j < 4; ++j) {
                    const float s = acc[j];
                    const float v = (yIr[rt][j] == yq) ? -s : fmaxf(s, 0.f);
                    const int iloc = hi * 4 + j;
                    sum += (iloc < lo16) ? v : 0.f;   // strict i<j
                }
            } else {
#pragma unroll
                for (int j = 0; j < 4; ++j) {
                    const float s = acc[j];
                    sum += (yIr[rt][j] == yq) ? -s : fmaxf(s, 0.f);
                }
            }
        }
    }

    // ---- block reduction + single atomic ------------------------------------
#pragma unroll
    for (int off = 32; off > 0; off >>= 1) sum += __shfl_down(sum, off);
    if (lane == 0) wred[wv] = sum;
    __syncthreads();
    if (t == 0) {
        const float total = wred[0] + wred[1] + wred[2] + wred[3];
        atomicAdd(out, total * (1.0f / (float)N_PIX));
    }
}

extern "C" void kernel_launch(void* const* d_in, const int* in_sizes, int n_in,
                              void* d_out, int out_size, void* d_ws, size_t ws_size,
                              hipStream_t stream) {
    const float* emb = (const float*)d_in[0];
    const int*   lab = (const int*)d_in[1];
    float* out = (float*)d_out;
    float* rinv_g = (float*)d_ws;          // BATCH*NUM_LABELS floats

    hist_kernel<<<1, 1024, 0, stream>>>(lab, rinv_g, out);
    pair_kernel<<<NPAIRS, 256, 0, stream>>>(emb, lab, rinv_g, out);
}

// Round 11
// 42.692 us; speedup vs baseline: 4.1091x; 1.0130x over previous
//
#include <hip/hip_runtime.h>

#define NUM_LABELS 20
#define N_PIX 4096
#define C_DIM 16
#define BATCH 4

#define PTILE 128
#define PNT (N_PIX / PTILE)               // 32
#define PTPAIRS (PNT * (PNT + 1) / 2)     // 528
#define NPAIRS (BATCH * PTPAIRS)          // 2112

#define PREP_SLICES 16                    // blocks per batch (64 total)
#define NPREP (BATCH * PREP_SLICES)
#define KPAD 24                           // LDS row stride in shorts (48 B)

typedef __attribute__((ext_vector_type(8))) short bf16x8;
typedef __attribute__((ext_vector_type(4))) float f32x4;

__device__ __forceinline__ unsigned int bf16rne(float f) {
    unsigned int x = __float_as_uint(f);
    return (x + 0x7fffu + ((x >> 16) & 1u)) >> 16;
}

// ---------------- Kernel A: hist + normalize -> gT bf16; extra terms; out=0 -
// g = (1/cnt[y]) * normalize(center(x))
// extra[blk] = -0.5*sum_slice |g_f32|^2  (+ 0.5*#present for slice-0 blocks)
__global__ __launch_bounds__(256) void prep_kernel(
    const float* __restrict__ emb,         // [B][C][N]
    const int*   __restrict__ lab,         // [B][N]
    unsigned short* __restrict__ gT,       // [B][N][C] bf16
    float* __restrict__ extra,             // [NPREP]
    float* __restrict__ out)               // [1]
{
    const int blk = blockIdx.x;
    const int b  = blk / PREP_SLICES;
    const int sl = blk % PREP_SLICES;
    const int t  = threadIdx.x;
    const int wv = t >> 6;
    const int lane = t & 63;

    if (blk == 0 && t == 0) out[0] = 0.f;   // zero the accumulator (pre-pair)

    __shared__ int   hist[4][NUM_LABELS];
    __shared__ float rinv[NUM_LABELS];
    __shared__ float xt[C_DIM][256];
    __shared__ float wsum[4];

    for (int i = t; i < 4 * NUM_LABELS; i += 256) (&hist[0][0])[i] = 0;
    __syncthreads();

    const int* yb = lab + (size_t)b * N_PIX;
    for (int n = t; n < N_PIX; n += 256) atomicAdd(&hist[wv][yb[n]], 1);

    // coalesced stage of this slice's 256 pixels x 16 channels
    const float* xb = emb + (size_t)b * C_DIM * N_PIX + sl * 256;
#pragma unroll
    for (int c = 0; c < C_DIM; ++c) xt[c][t] = xb[(size_t)c * N_PIX + t];
    __syncthreads();

    if (t < NUM_LABELS) {
        const int c = hist[0][t] + hist[1][t] + hist[2][t] + hist[3][t];
        rinv[t] = (c > 0) ? 1.0f / (float)c : 0.0f;
    }
    __syncthreads();

    const int n = sl * 256 + t;
    float v[C_DIM];
    float s = 0.f;
#pragma unroll
    for (int c = 0; c < C_DIM; ++c) { v[c] = xt[c][t]; s += v[c]; }
    const float mean = s * (1.0f / C_DIM);
    float ss = 0.f;
#pragma unroll
    for (int c = 0; c < C_DIM; ++c) { v[c] -= mean; ss += v[c] * v[c]; }
    const float nrm = sqrtf(ss);
    const float w   = rinv[yb[n]];
    const float inv = (nrm > 0.f) ? (w / nrm) : 0.f;

    unsigned int u[8];
#pragma unroll
    for (int k = 0; k < 8; ++k) {
        const unsigned int lo = bf16rne(v[2 * k] * inv);
        const unsigned int hi = bf16rne(v[2 * k + 1] * inv);
        u[k] = lo | (hi << 16);
    }
    unsigned int* gp = (unsigned int*)(gT + ((size_t)b * N_PIX + n) * C_DIM);
    *reinterpret_cast<uint4*>(gp)     = make_uint4(u[0], u[1], u[2], u[3]);
    *reinterpret_cast<uint4*>(gp + 4) = make_uint4(u[4], u[5], u[6], u[7]);

    // -0.5 * sum |g_f32|^2 over this slice
    float sq = inv * inv * ss;
#pragma unroll
    for (int off = 32; off > 0; off >>= 1) sq += __shfl_down(sq, off);
    if (lane == 0) wsum[wv] = sq;
    __syncthreads();
    if (t == 0) {
        float e = -0.5f * (wsum[0] + wsum[1] + wsum[2] + wsum[3]);
        if (sl == 0) {                      // slice 0 owns + 0.5 * #present_b
            int p = 0;
#pragma unroll
            for (int l = 0; l < NUM_LABELS; ++l) p += (rinv[l] > 0.f) ? 1 : 0;
            e += 0.5f * (float)p;
        }
        extra[blk] = e;
    }
}

// ---------------- Kernel B: MFMA pairwise sum over i<j + atomic accumulate --
// block partial = sum_{i<j in tile-pair} (eq ? -s : max(s,0)); block 0 also
// folds in sum(extra).  out += partial / N.
__global__ __launch_bounds__(256) void pair_kernel(
    const unsigned short* __restrict__ gT, // [B][N][C] bf16
    const int*   __restrict__ lab,         // [B][N]
    const float* __restrict__ extra,       // [NPREP]
    float* __restrict__ out)               // [1]
{
    const int p  = blockIdx.x;
    const int b  = p / PTPAIRS;
    const int k0 = p % PTPAIRS;

    // decode upper-triangle tile pair (ti <= tj)
    const float nn = (float)PNT;
    int ti = (int)(((2.f * nn + 1.f) -
                    sqrtf((2.f * nn + 1.f) * (2.f * nn + 1.f) - 8.f * (float)k0)) * 0.5f);
    if (ti < 0) ti = 0;
    if (ti > PNT - 1) ti = PNT - 1;
    auto rowoff = [](int r) { return r * PNT - (r * (r - 1)) / 2; };
    while (ti > 0 && k0 < rowoff(ti)) --ti;
    while (ti < PNT - 1 && k0 >= rowoff(ti + 1)) ++ti;
    const int tj = ti + (k0 - rowoff(ti));
    const bool diag = (ti == tj);

    __shared__ unsigned short sI[PTILE * KPAD];
    __shared__ unsigned short sJ[PTILE * KPAD];
    __shared__ int syI[PTILE], syJ[PTILE];
    __shared__ float wred[4];

    const int t = threadIdx.x;
    const unsigned short* gb = gT + (size_t)b * N_PIX * C_DIM;

    {   // stage bf16 tiles: 128 rows x 32 B, one uint4 per thread per tile
        const int row = t >> 1, half = t & 1;
        const uint4 vI = *(reinterpret_cast<const uint4*>(gb + (size_t)(ti * PTILE + row) * C_DIM) + half);
        const uint4 vJ = *(reinterpret_cast<const uint4*>(gb + (size_t)(tj * PTILE + row) * C_DIM) + half);
        *reinterpret_cast<uint4*>(&sI[row * KPAD + half * 8]) = vI;
        *reinterpret_cast<uint4*>(&sJ[row * KPAD + half * 8]) = vJ;
    }
    if (t < PTILE) {
        syI[t] = lab[(size_t)b * N_PIX + ti * PTILE + t];
    } else {
        const int u = t - PTILE;
        syJ[u] = lab[(size_t)b * N_PIX + tj * PTILE + u];
    }

    // block 0: wave 0 reduces the 64 prep extras in parallel with staging
    float eterm = 0.f;
    if (p == 0 && t < 64) {
        float e = extra[t];
#pragma unroll
        for (int off = 32; off > 0; off >>= 1) e += __shfl_down(e, off);
        eterm = e;                          // valid on t==0
    }
    __syncthreads();

    const int wv   = t >> 6;
    const int lane = t & 63;
    const int lo16 = lane & 15;
    const int hi   = lane >> 4;            // 0..3
    const bool doread = (hi < 2);          // K=16 real; hi>=2 lanes hold zeros

    bf16x8 afrag[2] = {bf16x8{}, bf16x8{}};
    int    yIr[2][4];
#pragma unroll
    for (int rt = 0; rt < 2; ++rt) {
        const int rtile = wv * 2 + rt;
        if (doread)
            afrag[rt] = *reinterpret_cast<const bf16x8*>(&sI[(rtile * 16 + lo16) * KPAD + hi * 8]);
        const int4 yv = *reinterpret_cast<const int4*>(&syI[rtile * 16 + hi * 4]);
        yIr[rt][0] = yv.x; yIr[rt][1] = yv.y; yIr[rt][2] = yv.z; yIr[rt][3] = yv.w;
    }

    float sum = 0.f;
#pragma unroll
    for (int ct = 0; ct < 8; ++ct) {
        bf16x8 bfrag = bf16x8{};
        if (doread)
            bfrag = *reinterpret_cast<const bf16x8*>(&sJ[(ct * 16 + lo16) * KPAD + hi * 8]);
        const int yq = syJ[ct * 16 + lo16];
#pragma unroll
        for (int rt = 0; rt < 2; ++rt) {
            const int rtile = wv * 2 + rt;
            if (diag && rtile > ct) continue;      // below diagonal: skip
            f32x4 acc = {0.f, 0.f, 0.f, 0.f};
            acc = __builtin_amdgcn_mfma_f32_16x16x32_bf16(afrag[rt], bfrag, acc, 0, 0, 0);
            if (diag && rtile == ct) {
#pragma unroll
                for (int j = 0; j < 4; ++j) {
                    const float s = acc[j];
                    const float v = (yIr[rt][j] == yq) ? -s : fmaxf(s, 0.f);
                    const int iloc = hi * 4 + j;
                    sum += (iloc < lo16) ? v : 0.f;   // strict i<j
                }
            } else {
#pragma unroll
                for (int j = 0; j < 4; ++j) {
                    const float s = acc[j];
                    sum += (yIr[rt][j] == yq) ? -s : fmaxf(s, 0.f);
                }
            }
        }
    }

    // block reduction + single atomic
#pragma unroll
    for (int off = 32; off > 0; off >>= 1) sum += __shfl_down(sum, off);
    if (lane == 0) wred[wv] = sum;
    __syncthreads();
    if (t == 0) {
        float total = wred[0] + wred[1] + wred[2] + wred[3] + eterm;
        atomicAdd(out, total * (1.0f / (float)N_PIX));
    }
}

extern "C" void kernel_launch(void* const* d_in, const int* in_sizes, int n_in,
                              void* d_out, int out_size, void* d_ws, size_t ws_size,
                              hipStream_t stream) {
    const float* emb = (const float*)d_in[0];
    const int*   lab = (const int*)d_in[1];
    float* out = (float*)d_out;

    unsigned short* gT = (unsigned short*)d_ws;                        // B*N*C bf16
    float* extra = (float*)(gT + (size_t)BATCH * N_PIX * C_DIM);       // NPREP floats

    prep_kernel<<<NPREP, 256, 0, stream>>>(emb, lab, gT, extra, out);
    pair_kernel<<<NPAIRS, 256, 0, stream>>>(gT, lab, extra, out);
}

// Round 12
// 26.758 us; speedup vs baseline: 6.5559x; 1.5955x over previous
//
#include <hip/hip_runtime.h>

#define NUM_LABELS 20
#define N_PIX 4096
#define C_DIM 16
#define BATCH 4

#define PTILE 128
#define PNT (N_PIX / PTILE)               // 32
#define PTPAIRS (PNT * (PNT + 1) / 2)     // 528
#define NPAIRS (BATCH * PTPAIRS)          // 2112
#define NBLK 704                          // 3 contiguous pairs per block
#define BLK_PER_BATCH 176                 // 528 / 3
#define KPAD 24                           // LDS row stride in shorts (48 B)

typedef __attribute__((ext_vector_type(8))) short bf16x8;
typedef __attribute__((ext_vector_type(4))) float f32x4;

__device__ __forceinline__ unsigned int bf16rne(float f) {
    unsigned int x = __float_as_uint(f);
    return (x + 0x7fffu + ((x >> 16) & 1u)) >> 16;
}

// ---------------- Kernel 1: fused hist(ballot) + normalize + MFMA + epilogue
// partial[bk] = sum over 3 tile-pairs of sum_{i<j}(eq ? -s : max(s,0))
//   + diag tiles' -0.5*|g_f32|^2  + (k0==0 blocks) 0.5*#present_b
__global__ __launch_bounds__(256) void pair_kernel(
    const float* __restrict__ emb,        // [B][C][N]
    const int*   __restrict__ lab,        // [B][N]
    float* __restrict__ partials)         // [NBLK]
{
    const int bk   = blockIdx.x;          // 0..703
    const int b    = bk / BLK_PER_BATCH;  // batch (triples never cross batches)
    const int t    = threadIdx.x;
    const int lane = t & 63;
    const int wv   = t >> 6;

    __shared__ int   h[NUM_LABELS];
    __shared__ float rinv[NUM_LABELS];
    __shared__ unsigned short sI[PTILE * KPAD];
    __shared__ unsigned short sJ[PTILE * KPAD];
    __shared__ int   syI[PTILE], syJ[PTILE];
    __shared__ float wred[4];

    // ---- ballot histogram of this batch's 4096 labels ----------------------
    if (t < NUM_LABELS) h[t] = 0;
    __syncthreads();
    {
        const int* yb = lab + (size_t)b * N_PIX;
        int cnt[NUM_LABELS];
#pragma unroll
        for (int l = 0; l < NUM_LABELS; ++l) cnt[l] = 0;
        for (int it = 0; it < 16; ++it) {
            const int y = yb[wv * 1024 + it * 64 + lane];
#pragma unroll
            for (int l = 0; l < NUM_LABELS; ++l)
                cnt[l] += (int)__popcll(__ballot(y == l));
        }
        if (lane == 0) {
#pragma unroll
            for (int l = 0; l < NUM_LABELS; ++l) atomicAdd(&h[l], cnt[l]);
        }
    }
    __syncthreads();
    if (t < NUM_LABELS) rinv[t] = (h[t] > 0) ? 1.0f / (float)h[t] : 0.0f;
    __syncthreads();

    float sum = 0.f;
    if ((bk % BLK_PER_BATCH) == 0 && t == 0) {   // k0==0 block owns present term
        int p = 0;
#pragma unroll
        for (int l = 0; l < NUM_LABELS; ++l) p += (h[l] > 0) ? 1 : 0;
        sum += 0.5f * (float)p;
    }

    // ---- 3 contiguous tile-pairs ------------------------------------------
    for (int pi = 0; pi < 3; ++pi) {
        const int k0 = 3 * bk - b * PTPAIRS + pi;   // (3*bk)%528 + pi

        // decode upper-triangle tile pair (ti <= tj)
        const float nn = (float)PNT;
        int ti = (int)(((2.f * nn + 1.f) -
                        sqrtf((2.f * nn + 1.f) * (2.f * nn + 1.f) - 8.f * (float)k0)) * 0.5f);
        if (ti < 0) ti = 0;
        if (ti > PNT - 1) ti = PNT - 1;
        auto rowoff = [](int r) { return r * PNT - (r * (r - 1)) / 2; };
        while (ti > 0 && k0 < rowoff(ti)) --ti;
        while (ti < PNT - 1 && k0 >= rowoff(ti + 1)) ++ti;
        const int tj = ti + (k0 - rowoff(ti));
        const bool diag = (ti == tj);

        __syncthreads();   // previous iteration's LDS reads complete

        // ---- normalize own tiles straight from emb into LDS bf16 -----------
        {
            const int side = t >> 7;          // 0 -> tile I, 1 -> tile J
            const int row  = t & 127;
            const int tile = side ? tj : ti;
            const float* xb = emb + (size_t)b * C_DIM * N_PIX + tile * PTILE + row;

            float v[C_DIM];
            float s = 0.f;
#pragma unroll
            for (int c = 0; c < C_DIM; ++c) { v[c] = xb[(size_t)c * N_PIX]; s += v[c]; }
            const float mean = s * (1.0f / C_DIM);
            float ss = 0.f;
#pragma unroll
            for (int c = 0; c < C_DIM; ++c) { v[c] -= mean; ss += v[c] * v[c]; }
            const float nrm = sqrtf(ss);
            const int   y   = lab[b * N_PIX + tile * PTILE + row];
            const float w   = rinv[y];
            const float inv = (nrm > 0.f) ? (w / nrm) : 0.f;

            unsigned int u[8];
#pragma unroll
            for (int k = 0; k < 8; ++k) {
                const unsigned int lo = bf16rne(v[2 * k] * inv);
                const unsigned int hi = bf16rne(v[2 * k + 1] * inv);
                u[k] = lo | (hi << 16);
            }
            unsigned short* dst = side ? sJ : sI;
            *reinterpret_cast<uint4*>(&dst[row * KPAD])     = make_uint4(u[0], u[1], u[2], u[3]);
            *reinterpret_cast<uint4*>(&dst[row * KPAD + 8]) = make_uint4(u[4], u[5], u[6], u[7]);
            (side ? syJ : syI)[row] = y;

            if (diag && side == 0) sum -= 0.5f * (inv * inv * ss);
        }
        __syncthreads();

        // ---- MFMA + epilogue -----------------------------------------------
        const int lo16 = lane & 15;
        const int hi   = lane >> 4;            // 0..3
        const bool doread = (hi < 2);          // K=16 real; hi>=2 lanes zero

        bf16x8 afrag[2] = {bf16x8{}, bf16x8{}};
        int    yIr[2][4];
#pragma unroll
        for (int rt = 0; rt < 2; ++rt) {
            const int rtile = wv * 2 + rt;
            if (doread)
                afrag[rt] = *reinterpret_cast<const bf16x8*>(&sI[(rtile * 16 + lo16) * KPAD + hi * 8]);
            const int4 yv = *reinterpret_cast<const int4*>(&syI[rtile * 16 + hi * 4]);
            yIr[rt][0] = yv.x; yIr[rt][1] = yv.y; yIr[rt][2] = yv.z; yIr[rt][3] = yv.w;
        }

#pragma unroll
        for (int ct = 0; ct < 8; ++ct) {
            bf16x8 bfrag = bf16x8{};
            if (doread)
                bfrag = *reinterpret_cast<const bf16x8*>(&sJ[(ct * 16 + lo16) * KPAD + hi * 8]);
            const int yq = syJ[ct * 16 + lo16];
#pragma unroll
            for (int rt = 0; rt < 2; ++rt) {
                const int rtile = wv * 2 + rt;
                if (diag && rtile > ct) continue;      // below diagonal: skip
                f32x4 acc = {0.f, 0.f, 0.f, 0.f};
                acc = __builtin_amdgcn_mfma_f32_16x16x32_bf16(afrag[rt], bfrag, acc, 0, 0, 0);
                if (diag && rtile == ct) {
#pragma unroll
                    for (int j = 0; j < 4; ++j) {
                        const float s = acc[j];
                        const float v = (yIr[rt][j] == yq) ? -s : fmaxf(s, 0.f);
                        const int iloc = hi * 4 + j;
                        sum += (iloc < lo16) ? v : 0.f;   // strict i<j
                    }
                } else {
#pragma unroll
                    for (int j = 0; j < 4; ++j) {
                        const float s = acc[j];
                        sum += (yIr[rt][j] == yq) ? -s : fmaxf(s, 0.f);
                    }
                }
            }
        }
    }

    // ---- block reduction + plain store -------------------------------------
#pragma unroll
    for (int off = 32; off > 0; off >>= 1) sum += __shfl_down(sum, off);
    if (lane == 0) wred[wv] = sum;
    __syncthreads();
    if (t == 0) partials[bk] = wred[0] + wred[1] + wred[2] + wred[3];
}

// ---------------- Kernel 2: deterministic final reduce ----------------------
__global__ __launch_bounds__(256) void reduce_kernel(
    const float* __restrict__ partials, float* __restrict__ out)
{
    __shared__ double sd[256];
    const int t = threadIdx.x;
    double s = 0.0;
    for (int i = t; i < NBLK; i += 256) s += (double)partials[i];
    sd[t] = s;
    __syncthreads();
#pragma unroll
    for (int k = 128; k > 0; k >>= 1) {
        if (t < k) sd[t] += sd[t + k];
        __syncthreads();
    }
    if (t == 0) out[0] = (float)(sd[0] * (1.0 / (double)N_PIX));
}

extern "C" void kernel_launch(void* const* d_in, const int* in_sizes, int n_in,
                              void* d_out, int out_size, void* d_ws, size_t ws_size,
                              hipStream_t stream) {
    const float* emb = (const float*)d_in[0];
    const int*   lab = (const int*)d_in[1];
    float* out = (float*)d_out;
    float* partials = (float*)d_ws;        // NBLK floats

    pair_kernel<<<NBLK, 256, 0, stream>>>(emb, lab, partials);
    reduce_kernel<<<1, 256, 0, stream>>>(partials, out);
}

// Round 13
// 26.036 us; speedup vs baseline: 6.7379x; 1.0278x over previous
//
#include <hip/hip_runtime.h>

#define NUM_LABELS 20
#define N_PIX 4096
#define C_DIM 16
#define BATCH 4

#define PTILE 128
#define PNT (N_PIX / PTILE)               // 32
#define PTPAIRS (PNT * (PNT + 1) / 2)     // 528
#define NPAIRS (BATCH * PTPAIRS)          // 2112

#define PREP_SLICES 16                    // blocks per batch (64 total)
#define NPREP (BATCH * PREP_SLICES)
#define NPART (NPREP + NPAIRS)            // 64 prep extras + 2112 pair partials

typedef __attribute__((ext_vector_type(8))) short bf16x8;
typedef __attribute__((ext_vector_type(4))) float f32x4;

__device__ __forceinline__ unsigned int bf16rne(float f) {
    unsigned int x = __float_as_uint(f);
    return (x + 0x7fffu + ((x >> 16) & 1u)) >> 16;
}

// ---------------- Kernel A: ballot hist + normalize -> gT bf16 [B][N][C] ----
// g = (1/cnt[y]) * normalize(center(x))
// part[blk] = -0.5*sum_slice |g_f32|^2  (+ 0.5*#present for slice-0 blocks)
__global__ __launch_bounds__(256) void prep_kernel(
    const float* __restrict__ emb,         // [B][C][N]
    const int*   __restrict__ lab,         // [B][N]
    unsigned short* __restrict__ gT,       // [B][N][C] bf16
    float* __restrict__ part)              // [NPART]; we write [0..NPREP)
{
    const int blk  = blockIdx.x;
    const int b    = blk / PREP_SLICES;
    const int sl   = blk % PREP_SLICES;
    const int t    = threadIdx.x;
    const int wv   = t >> 6;
    const int lane = t & 63;

    __shared__ int   h[NUM_LABELS];
    __shared__ float rinv[NUM_LABELS];
    __shared__ float wsum[4];

    if (t < NUM_LABELS) h[t] = 0;
    __syncthreads();

    // ballot histogram of this batch's 4096 labels (wave wv covers 1024)
    {
        const int* yb = lab + (size_t)b * N_PIX;
        int cnt[NUM_LABELS];
#pragma unroll
        for (int l = 0; l < NUM_LABELS; ++l) cnt[l] = 0;
        for (int it = 0; it < 16; ++it) {
            const int y = yb[wv * 1024 + it * 64 + lane];
#pragma unroll
            for (int l = 0; l < NUM_LABELS; ++l)
                cnt[l] += (int)__popcll(__ballot(y == l));
        }
        if (lane == 0) {
#pragma unroll
            for (int l = 0; l < NUM_LABELS; ++l) atomicAdd(&h[l], cnt[l]);
        }
    }
    __syncthreads();
    if (t < NUM_LABELS) rinv[t] = (h[t] > 0) ? 1.0f / (float)h[t] : 0.0f;
    __syncthreads();

    // normalize one pixel per thread (loads are coalesced per channel)
    const int n = sl * 256 + t;
    const float* xb = emb + (size_t)b * C_DIM * N_PIX + n;
    float v[C_DIM];
    float s = 0.f;
#pragma unroll
    for (int c = 0; c < C_DIM; ++c) { v[c] = xb[(size_t)c * N_PIX]; s += v[c]; }
    const float mean = s * (1.0f / C_DIM);
    float ss = 0.f;
#pragma unroll
    for (int c = 0; c < C_DIM; ++c) { v[c] -= mean; ss += v[c] * v[c]; }
    const float nrm = sqrtf(ss);
    const float w   = rinv[lab[(size_t)b * N_PIX + n]];
    const float inv = (nrm > 0.f) ? (w / nrm) : 0.f;

    unsigned int u[8];
#pragma unroll
    for (int k = 0; k < 8; ++k) {
        const unsigned int lo = bf16rne(v[2 * k] * inv);
        const unsigned int hi = bf16rne(v[2 * k + 1] * inv);
        u[k] = lo | (hi << 16);
    }
    unsigned int* gp = (unsigned int*)(gT + ((size_t)b * N_PIX + n) * C_DIM);
    *reinterpret_cast<uint4*>(gp)     = make_uint4(u[0], u[1], u[2], u[3]);
    *reinterpret_cast<uint4*>(gp + 4) = make_uint4(u[4], u[5], u[6], u[7]);

    // -0.5 * sum |g_f32|^2 over this slice (+ present term on slice 0)
    float sq = inv * inv * ss;
#pragma unroll
    for (int off = 32; off > 0; off >>= 1) sq += __shfl_down(sq, off);
    if (lane == 0) wsum[wv] = sq;
    __syncthreads();
    if (t == 0) {
        float e = -0.5f * (wsum[0] + wsum[1] + wsum[2] + wsum[3]);
        if (sl == 0) {
            int p = 0;
#pragma unroll
            for (int l = 0; l < NUM_LABELS; ++l) p += (h[l] > 0) ? 1 : 0;
            e += 0.5f * (float)p;
        }
        part[blk] = e;
    }
}

// ---------------- Kernel B: LDS-free MFMA pairwise sum over i<j -------------
// Fragments stream straight from gT (L2-resident). No tile staging, no
// barriers in the hot path. part[NPREP+p] = sum_{i<j}(eq ? -s : max(s,0)).
__global__ __launch_bounds__(256) void pair_kernel(
    const unsigned short* __restrict__ gT, // [B][N][C] bf16
    const int*   __restrict__ lab,         // [B][N]
    float* __restrict__ part)              // [NPART]; we write [NPREP..)
{
    const int p  = blockIdx.x;
    const int b  = p / PTPAIRS;
    const int k0 = p % PTPAIRS;

    // decode upper-triangle tile pair (ti <= tj)
    const float nn = (float)PNT;
    int ti = (int)(((2.f * nn + 1.f) -
                    sqrtf((2.f * nn + 1.f) * (2.f * nn + 1.f) - 8.f * (float)k0)) * 0.5f);
    if (ti < 0) ti = 0;
    if (ti > PNT - 1) ti = PNT - 1;
    auto rowoff = [](int r) { return r * PNT - (r * (r - 1)) / 2; };
    while (ti > 0 && k0 < rowoff(ti)) --ti;
    while (ti < PNT - 1 && k0 >= rowoff(ti + 1)) ++ti;
    const int tj = ti + (k0 - rowoff(ti));
    const bool diag = (ti == tj);

    const int t    = threadIdx.x;
    const int wv   = t >> 6;
    const int lane = t & 63;
    const int lo16 = lane & 15;
    const int hi   = lane >> 4;            // 0..3
    const bool doread = (hi < 2);          // K=16 real; hi>=2 lanes hold zeros

    const unsigned short* gb = gT + (size_t)b * N_PIX * C_DIM;
    const int* lb = lab + (size_t)b * N_PIX;

    // A fragments + row labels for this wave's two 16-row tiles
    bf16x8 afrag[2] = {bf16x8{}, bf16x8{}};
    int    yIr[2][4];
#pragma unroll
    for (int rt = 0; rt < 2; ++rt) {
        const int rtile = wv * 2 + rt;
        const int arow  = ti * PTILE + rtile * 16 + lo16;
        if (doread)
            afrag[rt] = *reinterpret_cast<const bf16x8*>(gb + (size_t)arow * C_DIM + hi * 8);
        const int4 yv = *reinterpret_cast<const int4*>(lb + ti * PTILE + rtile * 16 + hi * 4);
        yIr[rt][0] = yv.x; yIr[rt][1] = yv.y; yIr[rt][2] = yv.z; yIr[rt][3] = yv.w;
    }

    float sum = 0.f;
#pragma unroll
    for (int ct = 0; ct < 8; ++ct) {
        const int brow = tj * PTILE + ct * 16 + lo16;
        bf16x8 bfrag = bf16x8{};
        if (doread)
            bfrag = *reinterpret_cast<const bf16x8*>(gb + (size_t)brow * C_DIM + hi * 8);
        const int yq = lb[tj * PTILE + ct * 16 + lo16];
#pragma unroll
        for (int rt = 0; rt < 2; ++rt) {
            const int rtile = wv * 2 + rt;
            if (diag && rtile > ct) continue;      // below diagonal: skip
            f32x4 acc = {0.f, 0.f, 0.f, 0.f};
            acc = __builtin_amdgcn_mfma_f32_16x16x32_bf16(afrag[rt], bfrag, acc, 0, 0, 0);
            if (diag && rtile == ct) {
#pragma unroll
                for (int j = 0; j < 4; ++j) {
                    const float s = acc[j];
                    const float v = (yIr[rt][j] == yq) ? -s : fmaxf(s, 0.f);
                    const int iloc = hi * 4 + j;
                    sum += (iloc < lo16) ? v : 0.f;   // strict i<j
                }
            } else {
#pragma unroll
                for (int j = 0; j < 4; ++j) {
                    const float s = acc[j];
                    sum += (yIr[rt][j] == yq) ? -s : fmaxf(s, 0.f);
                }
            }
        }
    }

    // block reduction + plain store
#pragma unroll
    for (int off = 32; off > 0; off >>= 1) sum += __shfl_down(sum, off);
    __shared__ float wred[4];
    if (lane == 0) wred[wv] = sum;
    __syncthreads();
    if (t == 0) part[NPREP + p] = wred[0] + wred[1] + wred[2] + wred[3];
}

// ---------------- Kernel C: deterministic final reduce ----------------------
__global__ __launch_bounds__(256) void reduce_kernel(
    const float* __restrict__ part, float* __restrict__ out)
{
    __shared__ double sd[256];
    const int t = threadIdx.x;
    double s = 0.0;
    for (int i = t; i < NPART; i += 256) s += (double)part[i];
    sd[t] = s;
    __syncthreads();
#pragma unroll
    for (int k = 128; k > 0; k >>= 1) {
        if (t < k) sd[t] += sd[t + k];
        __syncthreads();
    }
    if (t == 0) out[0] = (float)(sd[0] * (1.0 / (double)N_PIX));
}

extern "C" void kernel_launch(void* const* d_in, const int* in_sizes, int n_in,
                              void* d_out, int out_size, void* d_ws, size_t ws_size,
                              hipStream_t stream) {
    const float* emb = (const float*)d_in[0];
    const int*   lab = (const int*)d_in[1];
    float* out = (float*)d_out;

    unsigned short* gT = (unsigned short*)d_ws;                    // B*N*C bf16
    float* part = (float*)(gT + (size_t)BATCH * N_PIX * C_DIM);    // NPART floats

    prep_kernel<<<NPREP, 256, 0, stream>>>(emb, lab, gT, part);
    pair_kernel<<<NPAIRS, 256, 0, stream>>>(gT, lab, part);
    reduce_kernel<<<1, 256, 0, stream>>>(part, out);
}